// Round 13
// baseline (448.995 us; speedup 1.0000x reference)
//
#include <hip/hip_runtime.h>
#include <hip/hip_bf16.h>

#define N_NODES 50000
#define N_EDGES 800000
#define N_GRAPHS 256
#define IN_DIM 300
#define HID 256
#define ROWS_PAD 50048   // 391 * 128
#define GEMM_GB 391      // ROWS_PAD / 128 (128x256 tiles, gemm1)
#define GB2 782          // 128x128 tiles (gemm2/3)
#define EPB 1024         // edges per fill/count block (4 per thread)
#define FILLB 782        // ceil(800000/1024)
#define NB 196           // ceil(N_NODES/256)

typedef __bf16 bf16x8 __attribute__((ext_vector_type(8)));
typedef short  s16x8  __attribute__((ext_vector_type(8)));
typedef short  s16x4  __attribute__((ext_vector_type(4)));
typedef float  f32x4  __attribute__((ext_vector_type(4)));
typedef float  f32x2  __attribute__((ext_vector_type(2)));
typedef int    i32x4  __attribute__((ext_vector_type(4)));

static __device__ __forceinline__ ushort f2bf(float f) {
    union { float f; uint u; } v; v.f = f;
    uint u = v.u;
    uint r = (u + 0x7fffu + ((u >> 16) & 1u)) >> 16;
    return (ushort)r;
}
static __device__ __forceinline__ float bf2f(ushort b) {
    union { uint u; float f; } v; v.u = ((uint)b) << 16;
    return v.f;
}
static __device__ __forceinline__ unsigned char f2fp8(float f) {
    int pk = __builtin_amdgcn_cvt_pk_fp8_f32(f, f, 0, 0);  // OCP e4m3 on gfx950
    return (unsigned char)(pk & 0xff);
}

// ---------------- fused: weight transposes + degree histogram (4 edges/thr) ----

__global__ __launch_bounds__(256) void pre_k(const float* __restrict__ W1,
                                             const float* __restrict__ W2,
                                             const float* __restrict__ W3,
                                             ushort* __restrict__ Wt1,
                                             ushort* __restrict__ Wt2,
                                             ushort* __restrict__ Wt3,
                                             const int* __restrict__ dst,
                                             int* __restrict__ cnt) {
    int b = blockIdx.x;
    int n = threadIdx.x;
    if (b < 320) {
        int k = b;
        Wt1[(size_t)n * 320 + k] = (k < IN_DIM) ? f2bf(W1[(size_t)k * 256 + n]) : (ushort)0;
    } else if (b < 576) {
        int k = b - 320;
        Wt2[(size_t)n * 256 + k] = f2bf(W2[(size_t)k * 256 + n]);
    } else if (b < 832) {
        int k = b - 576;
        Wt3[(size_t)n * 256 + k] = f2bf(W3[(size_t)k * 256 + n]);
    } else {
        int e0 = (b - 832) * EPB + n * 4;
        if (e0 + 4 <= N_EDGES) {
            i32x4 d = *(const i32x4*)(dst + e0);
            atomicAdd(&cnt[d[0]], 1);
            atomicAdd(&cnt[d[1]], 1);
            atomicAdd(&cnt[d[2]], 1);
            atomicAdd(&cnt[d[3]], 1);
        } else {
            for (int j = 0; j < 4; ++j)
                if (e0 + j < N_EDGES) atomicAdd(&cnt[dst[e0 + j]], 1);
        }
    }
}

// ---------------- one-pass scan: per-block prefix + atomic base allocation -----
// CSR row ranges only need DISJOINTNESS, not ordering -> block bases may be
// assigned in any order. Also computes dinv and zeroes psum.

__global__ __launch_bounds__(256) void scan_atomic(const int* __restrict__ cnt,
                                                   int* __restrict__ cursor,
                                                   float* __restrict__ dinv,
                                                   int* __restrict__ gtop,
                                                   float* __restrict__ psum, int n) {
    __shared__ int s[256];
    __shared__ int sbase;
    int t = threadIdx.x;
    int i = blockIdx.x * 256 + t;
    // zero psum (grid-stride over G*HID = 65536 floats)
    for (int j = i; j < N_GRAPHS * HID; j += NB * 256) psum[j] = 0.f;
    int v = (i < n) ? cnt[i] : 0;
    if (i < n) dinv[i] = rsqrtf((float)(v + 1));  // +1 self-loop
    s[t] = v;
    __syncthreads();
    for (int off = 1; off < 256; off <<= 1) {
        int u = (t >= off) ? s[t - off] : 0;
        __syncthreads();
        s[t] += u;
        __syncthreads();
    }
    if (t == 255) sbase = atomicAdd(gtop, s[255]);
    __syncthreads();
    if (i < n) cursor[i] = sbase + s[t] - v;  // exclusive prefix + base = row_start
}

// ---------------- GEMM body A: 128x256 tile (gemm1; A read once) ----------------

template <int KP, int KACT, bool AF32>
static __device__ __forceinline__ void gemm_body(int bx, const void* __restrict__ Ap,
                                                 const ushort* __restrict__ Bt,
                                                 unsigned char* __restrict__ C, int M,
                                                 ushort* As, ushort* Bs) {
    int t = threadIdx.x;
    int wave = t >> 6, lane = t & 63, quad = lane >> 4, l16 = lane & 15;
    int r0 = bx * 128;
    int arow = t & 127;
    int ahalf = t >> 7;

    f32x4 acc[8][4] = {};

    for (int kc = 0; kc < KP; kc += 64) {
#pragma unroll
        for (int i = 0; i < 8; ++i) {
            *(s16x8*)(Bs + i * 2048 + t * 8) =
                *(const s16x8*)(Bt + (size_t)t * KP + kc + i * 8);
        }
#pragma unroll
        for (int i = 0; i < 4; ++i) {
            int ks = 2 * i + ahalf;
            int kg = kc + ks * 8;
            if constexpr (AF32) {
                const float* Af = (const float*)Ap;
                int rg = r0 + arow; if (rg >= M) rg = M - 1;
                ushort tmp[8];
                if (kg + 8 <= KACT) {
                    f32x4 f0 = *(const f32x4*)(Af + (size_t)rg * KACT + kg);
                    f32x4 f1 = *(const f32x4*)(Af + (size_t)rg * KACT + kg + 4);
#pragma unroll
                    for (int j = 0; j < 4; ++j) { tmp[j] = f2bf(f0[j]); tmp[4 + j] = f2bf(f1[j]); }
                } else if (kg < KACT) {
                    f32x4 f0 = *(const f32x4*)(Af + (size_t)rg * KACT + kg);
#pragma unroll
                    for (int j = 0; j < 4; ++j) { tmp[j] = f2bf(f0[j]); tmp[4 + j] = 0; }
                } else {
#pragma unroll
                    for (int j = 0; j < 8; ++j) tmp[j] = 0;
                }
                *(s16x8*)(As + ks * 1024 + arow * 8) = *(const s16x8*)tmp;
            } else {
                const ushort* A = (const ushort*)Ap;
                *(s16x8*)(As + ks * 1024 + arow * 8) =
                    *(const s16x8*)(A + (size_t)(r0 + arow) * KP + kg);
            }
        }
        __syncthreads();

#pragma unroll
        for (int ks = 0; ks < 2; ++ks) {
            bf16x8 b[4];
#pragma unroll
            for (int ct = 0; ct < 4; ++ct)
                b[ct] = __builtin_bit_cast(bf16x8,
                    *(const s16x8*)(Bs + (ks * 4 + quad) * 2048 + (wave * 64 + ct * 16 + l16) * 8));
#pragma unroll
            for (int rt = 0; rt < 8; ++rt) {
                bf16x8 a = __builtin_bit_cast(bf16x8,
                    *(const s16x8*)(As + (ks * 4 + quad) * 1024 + (rt * 16 + l16) * 8));
#pragma unroll
                for (int ct = 0; ct < 4; ++ct)
                    acc[rt][ct] = __builtin_amdgcn_mfma_f32_16x16x32_bf16(a, b[ct], acc[rt][ct], 0, 0, 0);
            }
        }
        __syncthreads();
    }

#pragma unroll
    for (int rt = 0; rt < 8; ++rt) {
        int rowb = r0 + rt * 16 + quad * 4;
#pragma unroll
        for (int ct = 0; ct < 4; ++ct) {
            int col = wave * 64 + ct * 16 + l16;
#pragma unroll
            for (int i = 0; i < 4; ++i)
                C[(size_t)(rowb + i) * 256 + col] = f2fp8(acc[rt][ct][i]);
        }
    }
}

// ---------------- GEMM body B: 128x128 tile (gemm2/3; A is L3-hot) -------------

__global__ __launch_bounds__(256, 4) void gemm_k(const ushort* __restrict__ A,
                                                 const ushort* __restrict__ Bt,
                                                 unsigned char* __restrict__ C, int M) {
    __shared__ __align__(16) ushort As[8 * 128 * 8];   // 16 KB
    __shared__ __align__(16) ushort Bs[8 * 128 * 8];   // 16 KB
    const int KP = 256;
    int t = threadIdx.x;
    int wave = t >> 6, lane = t & 63, quad = lane >> 4, l16 = lane & 15;
    int wm = wave >> 1, wn = wave & 1;
    int r0 = (blockIdx.x >> 1) * 128;
    int n0 = (blockIdx.x & 1) * 128;
    int srow = t & 127;
    int shalf = t >> 7;

    f32x4 acc[4][4] = {};

    for (int kc = 0; kc < KP; kc += 64) {
#pragma unroll
        for (int i = 0; i < 4; ++i) {
            int ks = 2 * i + shalf;
            *(s16x8*)(Bs + ks * 1024 + srow * 8) =
                *(const s16x8*)(Bt + (size_t)(n0 + srow) * KP + kc + ks * 8);
            *(s16x8*)(As + ks * 1024 + srow * 8) =
                *(const s16x8*)(A + (size_t)(r0 + srow) * KP + kc + ks * 8);
        }
        __syncthreads();

#pragma unroll
        for (int ks2 = 0; ks2 < 2; ++ks2) {
            bf16x8 a[4], b[4];
#pragma unroll
            for (int ct = 0; ct < 4; ++ct)
                b[ct] = __builtin_bit_cast(bf16x8,
                    *(const s16x8*)(Bs + (ks2 * 4 + quad) * 1024 + (wn * 64 + ct * 16 + l16) * 8));
#pragma unroll
            for (int rt = 0; rt < 4; ++rt)
                a[rt] = __builtin_bit_cast(bf16x8,
                    *(const s16x8*)(As + (ks2 * 4 + quad) * 1024 + (wm * 64 + rt * 16 + l16) * 8));
#pragma unroll
            for (int rt = 0; rt < 4; ++rt)
#pragma unroll
                for (int ct = 0; ct < 4; ++ct)
                    acc[rt][ct] = __builtin_amdgcn_mfma_f32_16x16x32_bf16(a[rt], b[ct], acc[rt][ct], 0, 0, 0);
        }
        __syncthreads();
    }

#pragma unroll
    for (int rt = 0; rt < 4; ++rt) {
        int rowb = r0 + wm * 64 + rt * 16 + quad * 4;
#pragma unroll
        for (int ct = 0; ct < 4; ++ct) {
            int col = n0 + wn * 64 + ct * 16 + l16;
#pragma unroll
            for (int i = 0; i < 4; ++i)
                C[(size_t)(rowb + i) * 256 + col] = f2fp8(acc[rt][ct][i]);
        }
    }
}

// fused: gemm1 tiles (blocks [0,GEMM_GB)) + CSR fill ([GEMM_GB, +FILLB), 4 e/thr)
// launch_bounds(256,3): VGPR 128 + 48KB LDS -> 3 blocks/CU (was 2).
__global__ __launch_bounds__(256, 3) void gemm1_fill(const float* __restrict__ x,
                                                     const ushort* __restrict__ Wt1,
                                                     unsigned char* __restrict__ C, int M,
                                                     const int* __restrict__ src,
                                                     const int* __restrict__ dst,
                                                     int* __restrict__ cursor,
                                                     int* __restrict__ col) {
    __shared__ __align__(16) ushort As[8 * 128 * 8];
    __shared__ __align__(16) ushort Bs[8 * 256 * 8];
    int b = blockIdx.x;
    if (b < GEMM_GB) {
        gemm_body<320, IN_DIM, true>(b, x, Wt1, C, M, As, Bs);
    } else {
        int e0 = (b - GEMM_GB) * EPB + threadIdx.x * 4;
        if (e0 + 4 <= N_EDGES) {
            i32x4 d = *(const i32x4*)(dst + e0);
            i32x4 s = *(const i32x4*)(src + e0);
            int p0 = atomicAdd(&cursor[d[0]], 1);
            int p1 = atomicAdd(&cursor[d[1]], 1);
            int p2 = atomicAdd(&cursor[d[2]], 1);
            int p3 = atomicAdd(&cursor[d[3]], 1);
            col[p0] = s[0]; col[p1] = s[1]; col[p2] = s[2]; col[p3] = s[3];
        } else {
            for (int j = 0; j < 4; ++j) {
                int e = e0 + j;
                if (e < N_EDGES) {
                    int p = atomicAdd(&cursor[dst[e]], 1);
                    col[p] = src[e];
                }
            }
        }
    }
}

// ---------------- CSR aggregation: one wave per node, fp8 gather, 8-deep MLP ----
// start = cursor[n] - cnt[n]  (cursor holds row_end after fill).

template <bool TO_PSUM>
__global__ __launch_bounds__(256) void aggregate_fp8(const unsigned char* __restrict__ z,
                                                     ushort* __restrict__ out,
                                                     const int* __restrict__ cursor,
                                                     const int* __restrict__ cnt,
                                                     const int* __restrict__ col,
                                                     const float* __restrict__ dinv,
                                                     const float* __restrict__ bias, int relu,
                                                     const int* __restrict__ batch,
                                                     float* __restrict__ psum) {
    const uint* zu = (const uint*)z;
    int t = threadIdx.x;
    int wave = __builtin_amdgcn_readfirstlane(t >> 6);
    int lane = t & 63;
    int n = blockIdx.x * 4 + wave;
    int c = cnt[n];
    int start = cursor[n] - c;
    float dv = dinv[n];

    float a0 = 0.f, a1 = 0.f, a2 = 0.f, a3 = 0.f;

    int j = 0;
    for (; j + 8 <= c; j += 8) {
        int r[8]; float w[8]; uint v[8];
#pragma unroll
        for (int u = 0; u < 8; ++u) r[u] = col[start + j + u];
#pragma unroll
        for (int u = 0; u < 8; ++u) w[u] = dinv[r[u]];
#pragma unroll
        for (int u = 0; u < 8; ++u) v[u] = zu[(size_t)r[u] * 64 + lane];
#pragma unroll
        for (int u = 0; u < 8; ++u) {
            f32x2 p = __builtin_amdgcn_cvt_pk_f32_fp8(v[u], 0);
            f32x2 q = __builtin_amdgcn_cvt_pk_f32_fp8(v[u], 1);
            a0 += w[u] * p[0]; a1 += w[u] * p[1]; a2 += w[u] * q[0]; a3 += w[u] * q[1];
        }
    }
    for (; j + 4 <= c; j += 4) {
        int r[4]; float w[4]; uint v[4];
#pragma unroll
        for (int u = 0; u < 4; ++u) r[u] = col[start + j + u];
#pragma unroll
        for (int u = 0; u < 4; ++u) w[u] = dinv[r[u]];
#pragma unroll
        for (int u = 0; u < 4; ++u) v[u] = zu[(size_t)r[u] * 64 + lane];
#pragma unroll
        for (int u = 0; u < 4; ++u) {
            f32x2 p = __builtin_amdgcn_cvt_pk_f32_fp8(v[u], 0);
            f32x2 q = __builtin_amdgcn_cvt_pk_f32_fp8(v[u], 1);
            a0 += w[u] * p[0]; a1 += w[u] * p[1]; a2 += w[u] * q[0]; a3 += w[u] * q[1];
        }
    }
    for (; j < c; ++j) {
        int r = col[start + j];
        float w = dinv[r];
        uint v = zu[(size_t)r * 64 + lane];
        f32x2 p = __builtin_amdgcn_cvt_pk_f32_fp8(v, 0);
        f32x2 q = __builtin_amdgcn_cvt_pk_f32_fp8(v, 1);
        a0 += w * p[0]; a1 += w * p[1]; a2 += w * q[0]; a3 += w * q[1];
    }

    uint vs = zu[(size_t)n * 64 + lane];
    f32x2 sp = __builtin_amdgcn_cvt_pk_f32_fp8(vs, 0);
    f32x2 sq = __builtin_amdgcn_cvt_pk_f32_fp8(vs, 1);
    float sv[4] = {sp[0], sp[1], sq[0], sq[1]};
    f32x4 bv = *(const f32x4*)(bias + lane * 4);

    if constexpr (!TO_PSUM) {
        ushort o[4];
#pragma unroll
        for (int i = 0; i < 4; ++i) {
            float acc = (i == 0 ? a0 : i == 1 ? a1 : i == 2 ? a2 : a3);
            float r = dv * (acc + dv * sv[i]) + bv[i];
            if (relu) r = fmaxf(r, 0.f);
            o[i] = f2bf(r);
        }
        *(s16x4*)(out + (size_t)n * HID + (size_t)lane * 4) = *(const s16x4*)o;
    } else {
        __shared__ float sred[4][256];
        __shared__ int sg[4];
#pragma unroll
        for (int i = 0; i < 4; ++i) {
            float acc = (i == 0 ? a0 : i == 1 ? a1 : i == 2 ? a2 : a3);
            sred[wave][lane * 4 + i] = dv * (acc + dv * sv[i]) + bv[i];
        }
        if (lane == 0) sg[wave] = batch[n];
        __syncthreads();
        float acc = sred[0][t];
        int g = sg[0];
        for (int w = 1; w < 4; ++w) {
            int gw = sg[w];
            if (gw == g) acc += sred[w][t];
            else { atomicAdd(&psum[g * HID + t], acc); g = gw; acc = sred[w][t]; }
        }
        atomicAdd(&psum[g * HID + t], acc);
    }
}

// ---------------- fused head ----------------

__global__ __launch_bounds__(256) void head_k(const float* __restrict__ psum,
                                              const int* __restrict__ batch, int n,
                                              const float* __restrict__ Wc1, const float* __restrict__ bc1,
                                              const float* __restrict__ Wc2, const float* __restrict__ bc2,
                                              const float* __restrict__ Wc3, const float* __restrict__ bc3,
                                              float* __restrict__ out) {
    int g = blockIdx.x;
    int t = threadIdx.x;
    __shared__ float pr[256];
    __shared__ float l1s[16], p1s[16];
    __shared__ float l2s[64], p2s[64];
    int lo = 0, hi = n;
    while (lo < hi) { int mid = (lo + hi) >> 1; if (batch[mid] < g) lo = mid + 1; else hi = mid; }
    int start = lo;
    lo = start; hi = n;
    while (lo < hi) { int mid = (lo + hi) >> 1; if (batch[mid] < g + 1) lo = mid + 1; else hi = mid; }
    int c = lo - start;
    float inv_c = 1.f / (float)max(c, 1);
    pr[t] = psum[g * 256 + t] * inv_c;
    __syncthreads();
    if (t < 16) {
        float a = bc1[t];
        for (int k = 0; k < 256; ++k) a += pr[k] * Wc1[k * 16 + t];
        l1s[t] = a;
        out[g * 16 + t] = a;
    }
    __syncthreads();
    if (t == 0) {
        float m = -1e30f;
        for (int j = 0; j < 16; ++j) m = fmaxf(m, l1s[j]);
        float s = 0.f;
        for (int j = 0; j < 16; ++j) { float e = expf(l1s[j] - m); p1s[j] = e; s += e; }
        float inv = 1.f / s;
        for (int j = 0; j < 16; ++j) p1s[j] *= inv;
    }
    __syncthreads();
    if (t < 64) {
        float a = bc2[t];
        for (int k = 0; k < 256; ++k) a += pr[k] * Wc2[k * 64 + t];
        for (int k = 0; k < 16; ++k) a += p1s[k] * Wc2[(256 + k) * 64 + t];
        l2s[t] = a;
        out[4096 + g * 64 + t] = a;
    }
    __syncthreads();
    if (t == 0) {
        float m = -1e30f;
        for (int j = 0; j < 64; ++j) m = fmaxf(m, l2s[j]);
        float s = 0.f;
        for (int j = 0; j < 64; ++j) { float e = expf(l2s[j] - m); p2s[j] = e; s += e; }
        float inv = 1.f / s;
        for (int j = 0; j < 64; ++j) p2s[j] *= inv;
    }
    __syncthreads();
    {
        float a = bc3[t];
        for (int k = 0; k < 256; ++k) a += pr[k] * Wc3[k * 256 + t];
        for (int k = 0; k < 64; ++k) a += p2s[k] * Wc3[(256 + k) * 256 + t];
        out[4096 + 16384 + g * 256 + t] = a;
    }
}

// ---------------- launch ----------------

extern "C" void kernel_launch(void* const* d_in, const int* in_sizes, int n_in,
                              void* d_out, int out_size, void* d_ws, size_t ws_size,
                              hipStream_t stream) {
    const float* x    = (const float*)d_in[0];
    const int*   ei   = (const int*)d_in[1];
    const int*   batch= (const int*)d_in[2];
    const float* W1 = (const float*)d_in[3];  const float* b1 = (const float*)d_in[4];
    const float* W2 = (const float*)d_in[5];  const float* b2 = (const float*)d_in[6];
    const float* W3 = (const float*)d_in[7];  const float* b3 = (const float*)d_in[8];
    const float* Wc1= (const float*)d_in[9];  const float* bc1= (const float*)d_in[10];
    const float* Wc2= (const float*)d_in[11]; const float* bc2= (const float*)d_in[12];
    const float* Wc3= (const float*)d_in[13]; const float* bc3= (const float*)d_in[14];
    float* out = (float*)d_out;

    const int N = N_NODES, E = N_EDGES, G = N_GRAPHS;

    char* ws = (char*)d_ws;
    size_t off = 0;
    auto alloc = [&](size_t bytes) -> void* {
        void* p = ws + off;
        off = (off + bytes + 255) & ~(size_t)255;
        return p;
    };
    unsigned char* z = (unsigned char*)alloc((size_t)ROWS_PAD * HID);      // 12.8 MB fp8
    ushort* hb   = (ushort*)alloc((size_t)ROWS_PAD * HID * 2);             // 25.6 MB bf16
    ushort* Wt1  = (ushort*)alloc((size_t)256 * 320 * 2);
    ushort* Wt2  = (ushort*)alloc((size_t)256 * 256 * 2);
    ushort* Wt3  = (ushort*)alloc((size_t)256 * 256 * 2);
    int*   cnt    = (int*)alloc((size_t)(N + 1) * 4);  // +1: gtop at cnt[N]
    int*   cursor = (int*)alloc((size_t)N * 4);
    float* dinv   = (float*)alloc((size_t)N * 4);
    int*   col    = (int*)alloc((size_t)E * 4);
    float* psum   = (float*)alloc((size_t)G * HID * 4);
    (void)ws_size;

    const int* src = ei;
    const int* dst = ei + E;
    int* gtop = cnt + N;

    hipMemsetAsync(cnt, 0, (size_t)(N + 1) * 4, stream);

    // transpose weights + degree histogram (independent work, one dispatch)
    pre_k<<<832 + FILLB, 256, 0, stream>>>(W1, W2, W3, Wt1, Wt2, Wt3, dst, cnt);

    // one-pass scan (atomic base alloc) + dinv + psum zeroing
    scan_atomic<<<NB, 256, 0, stream>>>(cnt, cursor, dinv, gtop, psum, N);

    // gemm layer-1 overlapped with CSR fill (independent chains; gemm first)
    gemm1_fill<<<GEMM_GB + FILLB, 256, 0, stream>>>(x, Wt1, z, N, src, dst, cursor, col);

    aggregate_fp8<false><<<N / 4, 256, 0, stream>>>(z, hb, cursor, cnt, col, dinv, b1, 1, batch, psum);
    gemm_k<<<GB2, 256, 0, stream>>>(hb, Wt2, z, N);
    aggregate_fp8<false><<<N / 4, 256, 0, stream>>>(z, hb, cursor, cnt, col, dinv, b2, 1, batch, psum);
    gemm_k<<<GB2, 256, 0, stream>>>(hb, Wt3, z, N);
    // layer 3: aggregate straight into pooled sums (no hb write, no pool pass)
    aggregate_fp8<true><<<N / 4, 256, 0, stream>>>(z, hb, cursor, cnt, col, dinv, b3, 0, batch, psum);

    head_k<<<G, 256, 0, stream>>>(psum, batch, N, Wc1, bc1, Wc2, bc2, Wc3, bc3, out);
}

// Round 14
// 411.375 us; speedup vs baseline: 1.0915x; 1.0915x over previous
//
#include <hip/hip_runtime.h>
#include <hip/hip_bf16.h>

#define N_NODES 50000
#define N_EDGES 800000
#define N_GRAPHS 256
#define IN_DIM 300
#define HID 256
#define ROWS_PAD 50048   // 391 * 128
#define GEMM_GB 391      // ROWS_PAD / 128 (128x256 tiles, gemm1)
#define GB2 782          // 128x128 tiles (gemm2/3)
#define EPB 1024         // edges per fill/count block (4 per thread)
#define FILLB 782        // ceil(800000/1024)
#define NB 196           // ceil(N_NODES/256)

typedef __bf16 bf16x8 __attribute__((ext_vector_type(8)));
typedef short  s16x8  __attribute__((ext_vector_type(8)));
typedef short  s16x4  __attribute__((ext_vector_type(4)));
typedef float  f32x4  __attribute__((ext_vector_type(4)));
typedef float  f32x2  __attribute__((ext_vector_type(2)));
typedef int    i32x4  __attribute__((ext_vector_type(4)));

static __device__ __forceinline__ ushort f2bf(float f) {
    union { float f; uint u; } v; v.f = f;
    uint u = v.u;
    uint r = (u + 0x7fffu + ((u >> 16) & 1u)) >> 16;
    return (ushort)r;
}
static __device__ __forceinline__ float bf2f(ushort b) {
    union { uint u; float f; } v; v.u = ((uint)b) << 16;
    return v.f;
}
static __device__ __forceinline__ unsigned char f2fp8(float f) {
    int pk = __builtin_amdgcn_cvt_pk_fp8_f32(f, f, 0, 0);  // OCP e4m3 on gfx950
    return (unsigned char)(pk & 0xff);
}

// ---------------- fused: weight transposes + degree histogram (4 edges/thr) ----

__global__ __launch_bounds__(256) void pre_k(const float* __restrict__ W1,
                                             const float* __restrict__ W2,
                                             const float* __restrict__ W3,
                                             ushort* __restrict__ Wt1,
                                             ushort* __restrict__ Wt2,
                                             ushort* __restrict__ Wt3,
                                             const int* __restrict__ dst,
                                             int* __restrict__ cnt) {
    int b = blockIdx.x;
    int n = threadIdx.x;
    if (b < 320) {
        int k = b;
        Wt1[(size_t)n * 320 + k] = (k < IN_DIM) ? f2bf(W1[(size_t)k * 256 + n]) : (ushort)0;
    } else if (b < 576) {
        int k = b - 320;
        Wt2[(size_t)n * 256 + k] = f2bf(W2[(size_t)k * 256 + n]);
    } else if (b < 832) {
        int k = b - 576;
        Wt3[(size_t)n * 256 + k] = f2bf(W3[(size_t)k * 256 + n]);
    } else {
        int e0 = (b - 832) * EPB + n * 4;
        if (e0 + 4 <= N_EDGES) {
            i32x4 d = *(const i32x4*)(dst + e0);
            atomicAdd(&cnt[d[0]], 1);
            atomicAdd(&cnt[d[1]], 1);
            atomicAdd(&cnt[d[2]], 1);
            atomicAdd(&cnt[d[3]], 1);
        } else {
            for (int j = 0; j < 4; ++j)
                if (e0 + j < N_EDGES) atomicAdd(&cnt[dst[e0 + j]], 1);
        }
    }
}

// ---------------- one-pass scan: per-block prefix + atomic base allocation -----

__global__ __launch_bounds__(256) void scan_atomic(const int* __restrict__ cnt,
                                                   int* __restrict__ cursor,
                                                   float* __restrict__ dinv,
                                                   int* __restrict__ gtop,
                                                   float* __restrict__ psum, int n) {
    __shared__ int s[256];
    __shared__ int sbase;
    int t = threadIdx.x;
    int i = blockIdx.x * 256 + t;
    for (int j = i; j < N_GRAPHS * HID; j += NB * 256) psum[j] = 0.f;
    int v = (i < n) ? cnt[i] : 0;
    if (i < n) dinv[i] = rsqrtf((float)(v + 1));  // +1 self-loop
    s[t] = v;
    __syncthreads();
    for (int off = 1; off < 256; off <<= 1) {
        int u = (t >= off) ? s[t - off] : 0;
        __syncthreads();
        s[t] += u;
        __syncthreads();
    }
    if (t == 255) sbase = atomicAdd(gtop, s[255]);
    __syncthreads();
    if (i < n) cursor[i] = sbase + s[t] - v;
}

// ---------------- GEMM body A: 128x256 tile (gemm1; A read once) ----------------

template <int KP, int KACT, bool AF32>
static __device__ __forceinline__ void gemm_body(int bx, const void* __restrict__ Ap,
                                                 const ushort* __restrict__ Bt,
                                                 unsigned char* __restrict__ C, int M,
                                                 ushort* As, ushort* Bs) {
    int t = threadIdx.x;
    int wave = t >> 6, lane = t & 63, quad = lane >> 4, l16 = lane & 15;
    int r0 = bx * 128;
    int arow = t & 127;
    int ahalf = t >> 7;

    f32x4 acc[8][4] = {};

    for (int kc = 0; kc < KP; kc += 64) {
#pragma unroll
        for (int i = 0; i < 8; ++i) {
            *(s16x8*)(Bs + i * 2048 + t * 8) =
                *(const s16x8*)(Bt + (size_t)t * KP + kc + i * 8);
        }
#pragma unroll
        for (int i = 0; i < 4; ++i) {
            int ks = 2 * i + ahalf;
            int kg = kc + ks * 8;
            if constexpr (AF32) {
                const float* Af = (const float*)Ap;
                int rg = r0 + arow; if (rg >= M) rg = M - 1;
                ushort tmp[8];
                if (kg + 8 <= KACT) {
                    f32x4 f0 = *(const f32x4*)(Af + (size_t)rg * KACT + kg);
                    f32x4 f1 = *(const f32x4*)(Af + (size_t)rg * KACT + kg + 4);
#pragma unroll
                    for (int j = 0; j < 4; ++j) { tmp[j] = f2bf(f0[j]); tmp[4 + j] = f2bf(f1[j]); }
                } else if (kg < KACT) {
                    f32x4 f0 = *(const f32x4*)(Af + (size_t)rg * KACT + kg);
#pragma unroll
                    for (int j = 0; j < 4; ++j) { tmp[j] = f2bf(f0[j]); tmp[4 + j] = 0; }
                } else {
#pragma unroll
                    for (int j = 0; j < 8; ++j) tmp[j] = 0;
                }
                *(s16x8*)(As + ks * 1024 + arow * 8) = *(const s16x8*)tmp;
            } else {
                const ushort* A = (const ushort*)Ap;
                *(s16x8*)(As + ks * 1024 + arow * 8) =
                    *(const s16x8*)(A + (size_t)(r0 + arow) * KP + kg);
            }
        }
        __syncthreads();

#pragma unroll
        for (int ks = 0; ks < 2; ++ks) {
            bf16x8 b[4];
#pragma unroll
            for (int ct = 0; ct < 4; ++ct)
                b[ct] = __builtin_bit_cast(bf16x8,
                    *(const s16x8*)(Bs + (ks * 4 + quad) * 2048 + (wave * 64 + ct * 16 + l16) * 8));
#pragma unroll
            for (int rt = 0; rt < 8; ++rt) {
                bf16x8 a = __builtin_bit_cast(bf16x8,
                    *(const s16x8*)(As + (ks * 4 + quad) * 1024 + (rt * 16 + l16) * 8));
#pragma unroll
                for (int ct = 0; ct < 4; ++ct)
                    acc[rt][ct] = __builtin_amdgcn_mfma_f32_16x16x32_bf16(a, b[ct], acc[rt][ct], 0, 0, 0);
            }
        }
        __syncthreads();
    }

#pragma unroll
    for (int rt = 0; rt < 8; ++rt) {
        int rowb = r0 + rt * 16 + quad * 4;
#pragma unroll
        for (int ct = 0; ct < 4; ++ct) {
            int col = wave * 64 + ct * 16 + l16;
#pragma unroll
            for (int i = 0; i < 4; ++i)
                C[(size_t)(rowb + i) * 256 + col] = f2fp8(acc[rt][ct][i]);
        }
    }
}

// ---------------- GEMM body B: 128x128 tile (gemm2/3; A is L3-hot) -------------

__global__ __launch_bounds__(256, 4) void gemm_k(const ushort* __restrict__ A,
                                                 const ushort* __restrict__ Bt,
                                                 unsigned char* __restrict__ C, int M) {
    __shared__ __align__(16) ushort As[8 * 128 * 8];   // 16 KB
    __shared__ __align__(16) ushort Bs[8 * 128 * 8];   // 16 KB
    const int KP = 256;
    int t = threadIdx.x;
    int wave = t >> 6, lane = t & 63, quad = lane >> 4, l16 = lane & 15;
    int wm = wave >> 1, wn = wave & 1;
    int r0 = (blockIdx.x >> 1) * 128;
    int n0 = (blockIdx.x & 1) * 128;
    int srow = t & 127;
    int shalf = t >> 7;

    f32x4 acc[4][4] = {};

    for (int kc = 0; kc < KP; kc += 64) {
#pragma unroll
        for (int i = 0; i < 4; ++i) {
            int ks = 2 * i + shalf;
            *(s16x8*)(Bs + ks * 1024 + srow * 8) =
                *(const s16x8*)(Bt + (size_t)(n0 + srow) * KP + kc + ks * 8);
            *(s16x8*)(As + ks * 1024 + srow * 8) =
                *(const s16x8*)(A + (size_t)(r0 + srow) * KP + kc + ks * 8);
        }
        __syncthreads();

#pragma unroll
        for (int ks2 = 0; ks2 < 2; ++ks2) {
            bf16x8 a[4], b[4];
#pragma unroll
            for (int ct = 0; ct < 4; ++ct)
                b[ct] = __builtin_bit_cast(bf16x8,
                    *(const s16x8*)(Bs + (ks2 * 4 + quad) * 1024 + (wn * 64 + ct * 16 + l16) * 8));
#pragma unroll
            for (int rt = 0; rt < 4; ++rt)
                a[rt] = __builtin_bit_cast(bf16x8,
                    *(const s16x8*)(As + (ks2 * 4 + quad) * 1024 + (wm * 64 + rt * 16 + l16) * 8));
#pragma unroll
            for (int rt = 0; rt < 4; ++rt)
#pragma unroll
                for (int ct = 0; ct < 4; ++ct)
                    acc[rt][ct] = __builtin_amdgcn_mfma_f32_16x16x32_bf16(a[rt], b[ct], acc[rt][ct], 0, 0, 0);
        }
        __syncthreads();
    }

#pragma unroll
    for (int rt = 0; rt < 4; ++rt) {
        int rowb = r0 + wm * 64 + rt * 16 + quad * 4;
#pragma unroll
        for (int ct = 0; ct < 4; ++ct) {
            int col = n0 + wn * 64 + ct * 16 + l16;
#pragma unroll
            for (int i = 0; i < 4; ++i)
                C[(size_t)(rowb + i) * 256 + col] = f2fp8(acc[rt][ct][i]);
        }
    }
}

// fused: gemm1 tiles (blocks [0,GEMM_GB)) + CSR fill ([GEMM_GB, +FILLB), 4 e/thr)
// launch_bounds(256,2): VGPR 128 needed (8x4 f32x4 acc) — (256,3) spills (r13).
__global__ __launch_bounds__(256, 2) void gemm1_fill(const float* __restrict__ x,
                                                     const ushort* __restrict__ Wt1,
                                                     unsigned char* __restrict__ C, int M,
                                                     const int* __restrict__ src,
                                                     const int* __restrict__ dst,
                                                     int* __restrict__ cursor,
                                                     int* __restrict__ col) {
    __shared__ __align__(16) ushort As[8 * 128 * 8];
    __shared__ __align__(16) ushort Bs[8 * 256 * 8];
    int b = blockIdx.x;
    if (b < GEMM_GB) {
        gemm_body<320, IN_DIM, true>(b, x, Wt1, C, M, As, Bs);
    } else {
        int e0 = (b - GEMM_GB) * EPB + threadIdx.x * 4;
        if (e0 + 4 <= N_EDGES) {
            i32x4 d = *(const i32x4*)(dst + e0);
            i32x4 s = *(const i32x4*)(src + e0);
            int p0 = atomicAdd(&cursor[d[0]], 1);
            int p1 = atomicAdd(&cursor[d[1]], 1);
            int p2 = atomicAdd(&cursor[d[2]], 1);
            int p3 = atomicAdd(&cursor[d[3]], 1);
            col[p0] = s[0]; col[p1] = s[1]; col[p2] = s[2]; col[p3] = s[3];
        } else {
            for (int j = 0; j < 4; ++j) {
                int e = e0 + j;
                if (e < N_EDGES) {
                    int p = atomicAdd(&cursor[dst[e]], 1);
                    col[p] = src[e];
                }
            }
        }
    }
}

// ---------------- CSR aggregation: one wave per node, fp8 gather, 8-deep MLP ----
// start = cursor[n] - cnt[n]  (cursor holds row_end after fill).

template <bool TO_PSUM>
__global__ __launch_bounds__(256) void aggregate_fp8(const unsigned char* __restrict__ z,
                                                     ushort* __restrict__ out,
                                                     const int* __restrict__ cursor,
                                                     const int* __restrict__ cnt,
                                                     const int* __restrict__ col,
                                                     const float* __restrict__ dinv,
                                                     const float* __restrict__ bias, int relu,
                                                     const int* __restrict__ batch,
                                                     float* __restrict__ psum) {
    const uint* zu = (const uint*)z;
    int t = threadIdx.x;
    int wave = __builtin_amdgcn_readfirstlane(t >> 6);
    int lane = t & 63;
    int n = blockIdx.x * 4 + wave;
    int c = cnt[n];
    int start = cursor[n] - c;
    float dv = dinv[n];

    float a0 = 0.f, a1 = 0.f, a2 = 0.f, a3 = 0.f;

    int j = 0;
    for (; j + 8 <= c; j += 8) {
        int r[8]; float w[8]; uint v[8];
#pragma unroll
        for (int u = 0; u < 8; ++u) r[u] = col[start + j + u];
#pragma unroll
        for (int u = 0; u < 8; ++u) w[u] = dinv[r[u]];
#pragma unroll
        for (int u = 0; u < 8; ++u) v[u] = zu[(size_t)r[u] * 64 + lane];
#pragma unroll
        for (int u = 0; u < 8; ++u) {
            f32x2 p = __builtin_amdgcn_cvt_pk_f32_fp8(v[u], 0);
            f32x2 q = __builtin_amdgcn_cvt_pk_f32_fp8(v[u], 1);
            a0 += w[u] * p[0]; a1 += w[u] * p[1]; a2 += w[u] * q[0]; a3 += w[u] * q[1];
        }
    }
    for (; j + 4 <= c; j += 4) {
        int r[4]; float w[4]; uint v[4];
#pragma unroll
        for (int u = 0; u < 4; ++u) r[u] = col[start + j + u];
#pragma unroll
        for (int u = 0; u < 4; ++u) w[u] = dinv[r[u]];
#pragma unroll
        for (int u = 0; u < 4; ++u) v[u] = zu[(size_t)r[u] * 64 + lane];
#pragma unroll
        for (int u = 0; u < 4; ++u) {
            f32x2 p = __builtin_amdgcn_cvt_pk_f32_fp8(v[u], 0);
            f32x2 q = __builtin_amdgcn_cvt_pk_f32_fp8(v[u], 1);
            a0 += w[u] * p[0]; a1 += w[u] * p[1]; a2 += w[u] * q[0]; a3 += w[u] * q[1];
        }
    }
    for (; j < c; ++j) {
        int r = col[start + j];
        float w = dinv[r];
        uint v = zu[(size_t)r * 64 + lane];
        f32x2 p = __builtin_amdgcn_cvt_pk_f32_fp8(v, 0);
        f32x2 q = __builtin_amdgcn_cvt_pk_f32_fp8(v, 1);
        a0 += w * p[0]; a1 += w * p[1]; a2 += w * q[0]; a3 += w * q[1];
    }

    uint vs = zu[(size_t)n * 64 + lane];
    f32x2 sp = __builtin_amdgcn_cvt_pk_f32_fp8(vs, 0);
    f32x2 sq = __builtin_amdgcn_cvt_pk_f32_fp8(vs, 1);
    float sv[4] = {sp[0], sp[1], sq[0], sq[1]};
    f32x4 bv = *(const f32x4*)(bias + lane * 4);

    if constexpr (!TO_PSUM) {
        ushort o[4];
#pragma unroll
        for (int i = 0; i < 4; ++i) {
            float acc = (i == 0 ? a0 : i == 1 ? a1 : i == 2 ? a2 : a3);
            float r = dv * (acc + dv * sv[i]) + bv[i];
            if (relu) r = fmaxf(r, 0.f);
            o[i] = f2bf(r);
        }
        *(s16x4*)(out + (size_t)n * HID + (size_t)lane * 4) = *(const s16x4*)o;
    } else {
        __shared__ float sred[4][256];
        __shared__ int sg[4];
#pragma unroll
        for (int i = 0; i < 4; ++i) {
            float acc = (i == 0 ? a0 : i == 1 ? a1 : i == 2 ? a2 : a3);
            sred[wave][lane * 4 + i] = dv * (acc + dv * sv[i]) + bv[i];
        }
        if (lane == 0) sg[wave] = batch[n];
        __syncthreads();
        float acc = sred[0][t];
        int g = sg[0];
        for (int w = 1; w < 4; ++w) {
            int gw = sg[w];
            if (gw == g) acc += sred[w][t];
            else { atomicAdd(&psum[g * HID + t], acc); g = gw; acc = sred[w][t]; }
        }
        atomicAdd(&psum[g * HID + t], acc);
    }
}

// ---------------- fused head ----------------

__global__ __launch_bounds__(256) void head_k(const float* __restrict__ psum,
                                              const int* __restrict__ batch, int n,
                                              const float* __restrict__ Wc1, const float* __restrict__ bc1,
                                              const float* __restrict__ Wc2, const float* __restrict__ bc2,
                                              const float* __restrict__ Wc3, const float* __restrict__ bc3,
                                              float* __restrict__ out) {
    int g = blockIdx.x;
    int t = threadIdx.x;
    __shared__ float pr[256];
    __shared__ float l1s[16], p1s[16];
    __shared__ float l2s[64], p2s[64];
    int lo = 0, hi = n;
    while (lo < hi) { int mid = (lo + hi) >> 1; if (batch[mid] < g) lo = mid + 1; else hi = mid; }
    int start = lo;
    lo = start; hi = n;
    while (lo < hi) { int mid = (lo + hi) >> 1; if (batch[mid] < g + 1) lo = mid + 1; else hi = mid; }
    int c = lo - start;
    float inv_c = 1.f / (float)max(c, 1);
    pr[t] = psum[g * 256 + t] * inv_c;
    __syncthreads();
    if (t < 16) {
        float a = bc1[t];
        for (int k = 0; k < 256; ++k) a += pr[k] * Wc1[k * 16 + t];
        l1s[t] = a;
        out[g * 16 + t] = a;
    }
    __syncthreads();
    if (t == 0) {
        float m = -1e30f;
        for (int j = 0; j < 16; ++j) m = fmaxf(m, l1s[j]);
        float s = 0.f;
        for (int j = 0; j < 16; ++j) { float e = expf(l1s[j] - m); p1s[j] = e; s += e; }
        float inv = 1.f / s;
        for (int j = 0; j < 16; ++j) p1s[j] *= inv;
    }
    __syncthreads();
    if (t < 64) {
        float a = bc2[t];
        for (int k = 0; k < 256; ++k) a += pr[k] * Wc2[k * 64 + t];
        for (int k = 0; k < 16; ++k) a += p1s[k] * Wc2[(256 + k) * 64 + t];
        l2s[t] = a;
        out[4096 + g * 64 + t] = a;
    }
    __syncthreads();
    if (t == 0) {
        float m = -1e30f;
        for (int j = 0; j < 64; ++j) m = fmaxf(m, l2s[j]);
        float s = 0.f;
        for (int j = 0; j < 64; ++j) { float e = expf(l2s[j] - m); p2s[j] = e; s += e; }
        float inv = 1.f / s;
        for (int j = 0; j < 64; ++j) p2s[j] *= inv;
    }
    __syncthreads();
    {
        float a = bc3[t];
        for (int k = 0; k < 256; ++k) a += pr[k] * Wc3[k * 256 + t];
        for (int k = 0; k < 64; ++k) a += p2s[k] * Wc3[(256 + k) * 256 + t];
        out[4096 + 16384 + g * 256 + t] = a;
    }
}

// ---------------- launch ----------------

extern "C" void kernel_launch(void* const* d_in, const int* in_sizes, int n_in,
                              void* d_out, int out_size, void* d_ws, size_t ws_size,
                              hipStream_t stream) {
    const float* x    = (const float*)d_in[0];
    const int*   ei   = (const int*)d_in[1];
    const int*   batch= (const int*)d_in[2];
    const float* W1 = (const float*)d_in[3];  const float* b1 = (const float*)d_in[4];
    const float* W2 = (const float*)d_in[5];  const float* b2 = (const float*)d_in[6];
    const float* W3 = (const float*)d_in[7];  const float* b3 = (const float*)d_in[8];
    const float* Wc1= (const float*)d_in[9];  const float* bc1= (const float*)d_in[10];
    const float* Wc2= (const float*)d_in[11]; const float* bc2= (const float*)d_in[12];
    const float* Wc3= (const float*)d_in[13]; const float* bc3= (const float*)d_in[14];
    float* out = (float*)d_out;

    const int N = N_NODES, E = N_EDGES, G = N_GRAPHS;

    char* ws = (char*)d_ws;
    size_t off = 0;
    auto alloc = [&](size_t bytes) -> void* {
        void* p = ws + off;
        off = (off + bytes + 255) & ~(size_t)255;
        return p;
    };
    unsigned char* z = (unsigned char*)alloc((size_t)ROWS_PAD * HID);      // 12.8 MB fp8
    ushort* hb   = (ushort*)alloc((size_t)ROWS_PAD * HID * 2);             // 25.6 MB bf16
    ushort* Wt1  = (ushort*)alloc((size_t)256 * 320 * 2);
    ushort* Wt2  = (ushort*)alloc((size_t)256 * 256 * 2);
    ushort* Wt3  = (ushort*)alloc((size_t)256 * 256 * 2);
    int*   cnt    = (int*)alloc((size_t)(N + 1) * 4);  // +1: gtop at cnt[N]
    int*   cursor = (int*)alloc((size_t)N * 4);
    float* dinv   = (float*)alloc((size_t)N * 4);
    int*   col    = (int*)alloc((size_t)E * 4);
    float* psum   = (float*)alloc((size_t)G * HID * 4);
    (void)ws_size;

    const int* src = ei;
    const int* dst = ei + E;
    int* gtop = cnt + N;

    hipMemsetAsync(cnt, 0, (size_t)(N + 1) * 4, stream);

    // transpose weights + degree histogram (independent work, one dispatch)
    pre_k<<<832 + FILLB, 256, 0, stream>>>(W1, W2, W3, Wt1, Wt2, Wt3, dst, cnt);

    // one-pass scan (atomic base alloc) + dinv + psum zeroing
    scan_atomic<<<NB, 256, 0, stream>>>(cnt, cursor, dinv, gtop, psum, N);

    // gemm layer-1 overlapped with CSR fill (independent chains; gemm first)
    gemm1_fill<<<GEMM_GB + FILLB, 256, 0, stream>>>(x, Wt1, z, N, src, dst, cursor, col);

    aggregate_fp8<false><<<N / 4, 256, 0, stream>>>(z, hb, cursor, cnt, col, dinv, b1, 1, batch, psum);
    gemm_k<<<GB2, 256, 0, stream>>>(hb, Wt2, z, N);
    aggregate_fp8<false><<<N / 4, 256, 0, stream>>>(z, hb, cursor, cnt, col, dinv, b2, 1, batch, psum);
    gemm_k<<<GB2, 256, 0, stream>>>(hb, Wt3, z, N);
    // layer 3: aggregate straight into pooled sums (no hb write, no pool pass)
    aggregate_fp8<true><<<N / 4, 256, 0, stream>>>(z, hb, cursor, cnt, col, dinv, b3, 0, batch, psum);

    head_k<<<G, 256, 0, stream>>>(psum, batch, N, Wc1, bc1, Wc2, bc2, Wc3, bc3, out);
}